// Round 3
// baseline (198.464 us; speedup 1.0000x reference)
//
#include <hip/hip_runtime.h>
#include <math.h>

#define B_  2
#define D_  1536
#define L_  2048
#define N_  16
#define NH  8                 // states per half-wave
#define LC  128               // chunk length along L (32 segs x 4 elems)
#define NCHUNK (L_ / LC)      // 16
#define NCH (B_ * D_)         // 3072 channels
#define LOG2E 1.4426950408889634f
#define LN2   0.6931471805599453f

typedef float f4 __attribute__((ext_vector_type(4)));
typedef float f8 __attribute__((ext_vector_type(8)));

__device__ __forceinline__ float exp2f_(float v) { return __builtin_amdgcn_exp2f(v); }
__device__ __forceinline__ float log2f_(float v) { return __builtin_amdgcn_logf(v); }
__device__ __forceinline__ float rcpf_(float v)  { return __builtin_amdgcn_rcpf(v); }

__device__ __forceinline__ float softplus_f(float v) {
    float t = exp2f_(v * LOG2E);                   // e^v
    float r = LN2 * log2f_(1.0f + t);              // ln(1+e^v)
    return (v > 20.0f) ? v : r;
}
__device__ __forceinline__ f8 splat8(float v) { f8 r = {v,v,v,v,v,v,v,v}; return r; }
__device__ __forceinline__ f8 exp2v8(f8 a) {
    f8 r;
    r[0]=exp2f_(a[0]); r[1]=exp2f_(a[1]); r[2]=exp2f_(a[2]); r[3]=exp2f_(a[3]);
    r[4]=exp2f_(a[4]); r[5]=exp2f_(a[5]); r[6]=exp2f_(a[6]); r[7]=exp2f_(a[7]);
    return r;
}
__device__ __forceinline__ float dot8(f8 a, f8 b) {
    float p0 = fmaf(a[0], b[0], a[1]*b[1]);
    float p1 = fmaf(a[2], b[2], a[3]*b[3]);
    float p2 = fmaf(a[4], b[4], a[5]*b[5]);
    float p3 = fmaf(a[6], b[6], a[7]*b[7]);
    return (p0 + p1) + (p2 + p3);
}

// DPP move with explicit identity for invalid/masked lanes (bound_ctrl=false
// and masked rows both produce `old`).
#define DPP_ROW_SHR(N) (0x110 + (N))
#define DPP_ROW_BCAST15 0x142
#define DPP_WAVE_SHR1   0x138
template<int CTRL, int RMASK>
__device__ __forceinline__ float updpp(float old, float v) {
    return __int_as_float(__builtin_amdgcn_update_dpp(
        __float_as_int(old), __float_as_int(v), CTRL, RMASK, 0xF, false));
}

// One wave (= one 64-thread block) per channel.
// lane=(g,s): g=lane>>5 owns 8 of 16 states, s=lane&31 owns a 4-elem segment.
//
// Round 3: the ENTIRE per-chunk operand set (delta, x, z, 8 B rows, 8 C rows
// = 19 f4) is register double-buffered one chunk ahead.  Round 2 prefetched
// only delta/x/B and gained 13%; C/z were still same-body loads whose latency
// (under the 3-wave 20-load-per-chunk burst through L1/L2) drifted into
// pass 2's first dot8.  Now a body issues only NEXT-chunk loads at its top and
// computes exclusively from registers filled one full body (~2000 cy) earlier
// — the per-body vmcnt wait covers loads issued an entire chunk ago.
// Last chunk clamps the prefetch to re-read the CURRENT chunk (L1-hot) rather
// than wrapping to chunk 0 (keeps FETCH_SIZE clean).
// VGPR budget: measured 84 with the 10-f4 buffer; +9 f4 ≈ 120-140, under the
// 170 cap from __launch_bounds__(64,3).  Spill tripwire: WRITE_SIZE != 24576KB.
__global__ __launch_bounds__(64, 3)
void ssm_scan_kernel(const float* __restrict__ x,
                     const float* __restrict__ delta,
                     const float* __restrict__ A,
                     const float* __restrict__ Bm,
                     const float* __restrict__ Cm,
                     const float* __restrict__ Dv,
                     const float* __restrict__ z,
                     const float* __restrict__ dbias,
                     float* __restrict__ out)
{
    const int lane = threadIdx.x;      // 0..63
    const int s    = lane & 31;
    const int g    = lane >> 5;
    const int ch   = blockIdx.x;       // one channel per wave
    const int b    = ch / D_;
    const int d    = ch - b * D_;

    const float bias = dbias[d];
    const float Dd   = Dv[d];

    const float* Ab = A + d * N_ + NH * g;
    f8 A2v;
    A2v[0]=Ab[0]*LOG2E; A2v[1]=Ab[1]*LOG2E; A2v[2]=Ab[2]*LOG2E; A2v[3]=Ab[3]*LOG2E;
    A2v[4]=Ab[4]*LOG2E; A2v[5]=Ab[5]*LOG2E; A2v[6]=Ab[6]*LOG2E; A2v[7]=Ab[7]*LOG2E;

    const float* Bp = Bm + (size_t)b * (N_ * L_) + (size_t)(NH * g) * L_;
    const float* Cp = Cm + (size_t)b * (N_ * L_) + (size_t)(NH * g) * L_;
    const size_t chbase = (size_t)ch * L_;

    f8 carry = splat8(0.0f);

    // ---- full prefetch buffers (19 f4 each), manually double-buffered ----
    f4 P0_dv, P0_xv, P0_zv, P0_B0, P0_B1, P0_B2, P0_B3, P0_B4, P0_B5, P0_B6, P0_B7,
                            P0_C0, P0_C1, P0_C2, P0_C3, P0_C4, P0_C5, P0_C6, P0_C7;
    f4 P1_dv, P1_xv, P1_zv, P1_B0, P1_B1, P1_B2, P1_B3, P1_B4, P1_B5, P1_B6, P1_B7,
                            P1_C0, P1_C1, P1_C2, P1_C3, P1_C4, P1_C5, P1_C6, P1_C7;

#define PREF(BUF, OFF) \
    BUF##_dv = *(const f4*)(delta + chbase + (OFF)); \
    BUF##_xv = *(const f4*)(x     + chbase + (OFF)); \
    BUF##_zv = *(const f4*)(z     + chbase + (OFF)); \
    BUF##_B0 = *(const f4*)(Bp + 0 * L_ + (OFF)); \
    BUF##_B1 = *(const f4*)(Bp + 1 * L_ + (OFF)); \
    BUF##_B2 = *(const f4*)(Bp + 2 * L_ + (OFF)); \
    BUF##_B3 = *(const f4*)(Bp + 3 * L_ + (OFF)); \
    BUF##_B4 = *(const f4*)(Bp + 4 * L_ + (OFF)); \
    BUF##_B5 = *(const f4*)(Bp + 5 * L_ + (OFF)); \
    BUF##_B6 = *(const f4*)(Bp + 6 * L_ + (OFF)); \
    BUF##_B7 = *(const f4*)(Bp + 7 * L_ + (OFF)); \
    BUF##_C0 = *(const f4*)(Cp + 0 * L_ + (OFF)); \
    BUF##_C1 = *(const f4*)(Cp + 1 * L_ + (OFF)); \
    BUF##_C2 = *(const f4*)(Cp + 2 * L_ + (OFF)); \
    BUF##_C3 = *(const f4*)(Cp + 3 * L_ + (OFF)); \
    BUF##_C4 = *(const f4*)(Cp + 4 * L_ + (OFF)); \
    BUF##_C5 = *(const f4*)(Cp + 5 * L_ + (OFF)); \
    BUF##_C6 = *(const f4*)(Cp + 6 * L_ + (OFF)); \
    BUF##_C7 = *(const f4*)(Cp + 7 * L_ + (OFF));

    PREF(P0, s * 4)   // chunk 0

#define BODY(c, CUR, NXT) { \
    const int off  = (c) * LC + s * 4; \
    /* clamp: last chunk re-prefetches ITS OWN data (L1-hot) instead of wrapping */ \
    const int offn = (((c) == NCHUNK - 1) ? (c) : (c) + 1) * LC + s * 4; \
    /* ---- issue next-chunk loads; nothing below loads memory ---- */ \
    PREF(NXT, offn) \
    /* ---- dt / u ---- */ \
    float dt0 = softplus_f(CUR##_dv.x + bias); \
    float dt1 = softplus_f(CUR##_dv.y + bias); \
    float dt2 = softplus_f(CUR##_dv.z + bias); \
    float dt3 = softplus_f(CUR##_dv.w + bias); \
    float u0 = dt0 * CUR##_xv.x, u1 = dt1 * CUR##_xv.y; \
    float u2 = dt2 * CUR##_xv.z, u3 = dt3 * CUR##_xv.w; \
    /* ---- per-element deltaA vectors (kept for pass 2) ---- */ \
    f8 e0 = exp2v8(splat8(dt0) * A2v); \
    f8 e1 = exp2v8(splat8(dt1) * A2v); \
    f8 e2 = exp2v8(splat8(dt2) * A2v); \
    f8 e3 = exp2v8(splat8(dt3) * A2v); \
    f8 P  = (e0 * e1) * (e2 * e3);     /* segment-total decay, no extra exps */ \
    /* ---- transpose B/C fragments to per-j state-vectors ---- */ \
    f8 tB0 = {CUR##_B0.x,CUR##_B1.x,CUR##_B2.x,CUR##_B3.x,CUR##_B4.x,CUR##_B5.x,CUR##_B6.x,CUR##_B7.x}; \
    f8 tB1 = {CUR##_B0.y,CUR##_B1.y,CUR##_B2.y,CUR##_B3.y,CUR##_B4.y,CUR##_B5.y,CUR##_B6.y,CUR##_B7.y}; \
    f8 tB2 = {CUR##_B0.z,CUR##_B1.z,CUR##_B2.z,CUR##_B3.z,CUR##_B4.z,CUR##_B5.z,CUR##_B6.z,CUR##_B7.z}; \
    f8 tB3 = {CUR##_B0.w,CUR##_B1.w,CUR##_B2.w,CUR##_B3.w,CUR##_B4.w,CUR##_B5.w,CUR##_B6.w,CUR##_B7.w}; \
    f8 uB0 = splat8(u0) * tB0; \
    f8 uB1 = splat8(u1) * tB1; \
    f8 uB2 = splat8(u2) * tB2; \
    f8 uB3 = splat8(u3) * tB3; \
    f8 SC0 = {CUR##_C0.x,CUR##_C1.x,CUR##_C2.x,CUR##_C3.x,CUR##_C4.x,CUR##_C5.x,CUR##_C6.x,CUR##_C7.x}; \
    f8 SC1 = {CUR##_C0.y,CUR##_C1.y,CUR##_C2.y,CUR##_C3.y,CUR##_C4.y,CUR##_C5.y,CUR##_C6.y,CUR##_C7.y}; \
    f8 SC2 = {CUR##_C0.z,CUR##_C1.z,CUR##_C2.z,CUR##_C3.z,CUR##_C4.z,CUR##_C5.z,CUR##_C6.z,CUR##_C7.z}; \
    f8 SC3 = {CUR##_C0.w,CUR##_C1.w,CUR##_C2.w,CUR##_C3.w,CUR##_C4.w,CUR##_C5.w,CUR##_C6.w,CUR##_C7.w}; \
    /* ---- pass 1: local 4-elem scan (start h=0) ---- */ \
    f8 S = uB0; \
    S = e1 * S + uB1; \
    S = e2 * S + uB2; \
    S = e3 * S + uB3; \
    /* ---- width-32 inclusive scan of (P,S), all DPP/VALU ---- */ \
    SCAN_STEP(DPP_ROW_SHR(1), 0xF) \
    SCAN_STEP(DPP_ROW_SHR(2), 0xF) \
    SCAN_STEP(DPP_ROW_SHR(4), 0xF) \
    SCAN_STEP(DPP_ROW_SHR(8), 0xF) \
    SCAN_STEP(DPP_ROW_BCAST15, 0xA)  /* rows 1,3 only; rows 0,2 keep neutral */ \
    /* ---- fold chunk carry; h entering this lane's segment ---- */ \
    f8 h; \
    _Pragma("unroll") \
    for (int i = 0; i < NH; ++i) { \
        float hinc = fmaf(carry[i], P[i], S[i]);            /* true inclusive state */ \
        float hup  = updpp<DPP_WAVE_SHR1, 0xF>(0.0f, hinc); /* lane n <- n-1 */ \
        h[i] = (s == 0) ? carry[i] : hup;                   /* fixes lanes 0 and 32 */ \
        carry[i] = __shfl(hinc, 31, 32);                    /* broadcast within half */ \
    } \
    /* ---- pass 2: recurrence (reusing e_j, uB_j); y_j = <h, C_j> ---- */ \
    h = e0 * h + uB0;  float y0 = dot8(h, SC0); \
    h = e1 * h + uB1;  float y1 = dot8(h, SC1); \
    h = e2 * h + uB2;  float y2 = dot8(h, SC2); \
    h = e3 * h + uB3;  float y3 = dot8(h, SC3); \
    /* ---- combine the two state-halves; epilogue; half-wave store ---- */ \
    y0 += __shfl_xor(y0, 32, 64); \
    y1 += __shfl_xor(y1, 32, 64); \
    y2 += __shfl_xor(y2, 32, 64); \
    y3 += __shfl_xor(y3, 32, 64); \
    if (g == 0) { \
        float s0 = rcpf_(1.0f + exp2f_(-CUR##_zv.x * LOG2E)); \
        float s1 = rcpf_(1.0f + exp2f_(-CUR##_zv.y * LOG2E)); \
        float s2 = rcpf_(1.0f + exp2f_(-CUR##_zv.z * LOG2E)); \
        float s3 = rcpf_(1.0f + exp2f_(-CUR##_zv.w * LOG2E)); \
        f4 ov = { (y0 + CUR##_xv.x * Dd) * (CUR##_zv.x * s0), \
                  (y1 + CUR##_xv.y * Dd) * (CUR##_zv.y * s1), \
                  (y2 + CUR##_xv.z * Dd) * (CUR##_zv.z * s2), \
                  (y3 + CUR##_xv.w * Dd) * (CUR##_zv.w * s3) }; \
        *(f4*)(out + chbase + off) = ov; \
    } \
}

#define SCAN_STEP(CTRL, RMASK) \
    { \
        _Pragma("unroll") \
        for (int i = 0; i < NH; ++i) { \
            float Pp = updpp<CTRL, RMASK>(1.0f, P[i]); \
            float Sp = updpp<CTRL, RMASK>(0.0f, S[i]); \
            S[i] = fmaf(Sp, P[i], S[i]);   /* uses pre-update P */ \
            P[i] = P[i] * Pp; \
        } \
    }

    for (int cc = 0; cc < NCHUNK; cc += 2) {
        BODY(cc,     P0, P1)
        BODY(cc + 1, P1, P0)
    }
}

extern "C" void kernel_launch(void* const* d_in, const int* in_sizes, int n_in,
                              void* d_out, int out_size, void* d_ws, size_t ws_size,
                              hipStream_t stream) {
    const float* x     = (const float*)d_in[0];
    const float* delta = (const float*)d_in[1];
    const float* A     = (const float*)d_in[2];
    const float* Bm    = (const float*)d_in[3];
    const float* Cm    = (const float*)d_in[4];
    const float* Dv    = (const float*)d_in[5];
    const float* z     = (const float*)d_in[6];
    const float* dbias = (const float*)d_in[7];
    float* out = (float*)d_out;

    dim3 grid(NCH);    // 3072 blocks = 1 wave = 1 channel each
    dim3 block(64);
    ssm_scan_kernel<<<grid, block, 0, stream>>>(x, delta, A, Bm, Cm, Dv, z, dbias, out);
}

// Round 4
// 170.618 us; speedup vs baseline: 1.1632x; 1.1632x over previous
//
#include <hip/hip_runtime.h>
#include <math.h>

#define B_  2
#define D_  1536
#define L_  2048
#define N_  16
#define NH  8                 // states per half-wave
#define LC  128               // chunk length along L (32 segs x 4 elems)
#define NCHUNK (L_ / LC)      // 16
#define NCH (B_ * D_)         // 3072 channels
#define LOG2E 1.4426950408889634f
#define LN2   0.6931471805599453f

typedef float f4 __attribute__((ext_vector_type(4)));
typedef float f8 __attribute__((ext_vector_type(8)));

__device__ __forceinline__ float exp2f_(float v) { return __builtin_amdgcn_exp2f(v); }
__device__ __forceinline__ float log2f_(float v) { return __builtin_amdgcn_logf(v); }
__device__ __forceinline__ float rcpf_(float v)  { return __builtin_amdgcn_rcpf(v); }

__device__ __forceinline__ float softplus_f(float v) {
    float t = exp2f_(v * LOG2E);                   // e^v
    float r = LN2 * log2f_(1.0f + t);              // ln(1+e^v)
    return (v > 20.0f) ? v : r;
}
__device__ __forceinline__ f8 splat8(float v) { f8 r = {v,v,v,v,v,v,v,v}; return r; }
__device__ __forceinline__ f8 exp2v8(f8 a) {
    f8 r;
    r[0]=exp2f_(a[0]); r[1]=exp2f_(a[1]); r[2]=exp2f_(a[2]); r[3]=exp2f_(a[3]);
    r[4]=exp2f_(a[4]); r[5]=exp2f_(a[5]); r[6]=exp2f_(a[6]); r[7]=exp2f_(a[7]);
    return r;
}
__device__ __forceinline__ float dot8(f8 a, f8 b) {
    float p0 = fmaf(a[0], b[0], a[1]*b[1]);
    float p1 = fmaf(a[2], b[2], a[3]*b[3]);
    float p2 = fmaf(a[4], b[4], a[5]*b[5]);
    float p3 = fmaf(a[6], b[6], a[7]*b[7]);
    return (p0 + p1) + (p2 + p3);
}

// DPP helpers.
// updpp: old-value semantics (masked rows / invalid lanes produce `old`).
// dpp0 : bound_ctrl=true, invalid lanes read 0 (additive identity) — single
//        v_mov_b32 dpp when row_mask is 0xF (no old-materialization mov).
#define DPP_ROW_SHR(N) (0x110 + (N))
#define DPP_ROW_BCAST15 0x142
#define DPP_WAVE_SHR1   0x138
template<int CTRL, int RMASK>
__device__ __forceinline__ float updpp(float old, float v) {
    return __int_as_float(__builtin_amdgcn_update_dpp(
        __float_as_int(old), __float_as_int(v), CTRL, RMASK, 0xF, false));
}
template<int CTRL, int RMASK>
__device__ __forceinline__ float dpp0(float v) {
    return __int_as_float(__builtin_amdgcn_update_dpp(
        0, __float_as_int(v), CTRL, RMASK, 0xF, true));
}

// One wave (= one 64-thread block) per channel.
// lane=(g,s): g=lane>>5 owns 8 of 16 states, s=lane&31 owns a 4-elem segment.
//
// Round 4 (on the round-2 76us base; round-3's full-operand prefetch SPILLED —
// peak liveness ~200 floats > the 168-reg cap, WRITE_SIZE 24.6->53MB):
//  * F/S reformulation: pass 1 keeps prefix products F_j=e0..e_j and partial
//    states S_j (F0,S0 alias e0,uB0).  e1-3/uB1-3 die at pass 1 (-16 live regs
//    through the scan) and pass 2 becomes 3 INDEPENDENT t_j=F_j*h_in+S_j dots
//    (was a 4-deep serial chain) -> ILP while the scan chain would stall.
//    hinc (the fold value) IS the post-elem-3 state -> y3=dot8(hinc,SC3), so
//    the scan mutates F3/S3 in place and pass 2 drops one fma row.
//  * S-shifts / hup use bound_ctrl=true (0-fill = additive identity): single
//    dpp-mov for all row_mask=0xF steps (~40 fewer instrs/body).  P keeps
//    old=1.0 (multiplicative identity has no bound_ctrl form).
//  * Prefetch (delta/x/B one chunk ahead, as round 2) issues BEFORE the C/z
//    loads so next body's dv retires with minimal vmcnt dependency.
// C/z stay same-body: B/C are L2-resident (1MB shared by all channels),
// ~200cy latency vs ~1000cy of cover — never the stall (round-3 lesson).
__global__ __launch_bounds__(64, 3)
void ssm_scan_kernel(const float* __restrict__ x,
                     const float* __restrict__ delta,
                     const float* __restrict__ A,
                     const float* __restrict__ Bm,
                     const float* __restrict__ Cm,
                     const float* __restrict__ Dv,
                     const float* __restrict__ z,
                     const float* __restrict__ dbias,
                     float* __restrict__ out)
{
    const int lane = threadIdx.x;      // 0..63
    const int s    = lane & 31;
    const int g    = lane >> 5;
    const int ch   = blockIdx.x;       // one channel per wave
    const int b    = ch / D_;
    const int d    = ch - b * D_;

    const float bias = dbias[d];
    const float Dd   = Dv[d];

    const float* Ab = A + d * N_ + NH * g;
    f8 A2v;
    A2v[0]=Ab[0]*LOG2E; A2v[1]=Ab[1]*LOG2E; A2v[2]=Ab[2]*LOG2E; A2v[3]=Ab[3]*LOG2E;
    A2v[4]=Ab[4]*LOG2E; A2v[5]=Ab[5]*LOG2E; A2v[6]=Ab[6]*LOG2E; A2v[7]=Ab[7]*LOG2E;

    const float* Bp = Bm + (size_t)b * (N_ * L_) + (size_t)(NH * g) * L_;
    const float* Cp = Cm + (size_t)b * (N_ * L_) + (size_t)(NH * g) * L_;
    const size_t chbase = (size_t)ch * L_;

    f8 carry = splat8(0.0f);

    // ---- early-consumed operands (delta, x, B) double-buffered 1 chunk ahead ----
    f4 P0_dv = *(const f4*)(delta + chbase + s * 4);
    f4 P0_xv = *(const f4*)(x     + chbase + s * 4);
    f4 P0_B0 = *(const f4*)(Bp + 0 * L_ + s * 4);
    f4 P0_B1 = *(const f4*)(Bp + 1 * L_ + s * 4);
    f4 P0_B2 = *(const f4*)(Bp + 2 * L_ + s * 4);
    f4 P0_B3 = *(const f4*)(Bp + 3 * L_ + s * 4);
    f4 P0_B4 = *(const f4*)(Bp + 4 * L_ + s * 4);
    f4 P0_B5 = *(const f4*)(Bp + 5 * L_ + s * 4);
    f4 P0_B6 = *(const f4*)(Bp + 6 * L_ + s * 4);
    f4 P0_B7 = *(const f4*)(Bp + 7 * L_ + s * 4);
    f4 P1_dv, P1_xv, P1_B0, P1_B1, P1_B2, P1_B3, P1_B4, P1_B5, P1_B6, P1_B7;

#define BODY(c, CUR, NXT) { \
    const int off  = (c) * LC + s * 4; \
    /* clamp: last chunk re-prefetches ITS OWN data (L1-hot) instead of wrapping */ \
    const int offn = (((c) == NCHUNK - 1) ? (c) : (c) + 1) * LC + s * 4; \
    /* ---- next-chunk early-use prefetch FIRST (dv retires soonest) ---- */ \
    NXT##_dv = *(const f4*)(delta + chbase + offn); \
    NXT##_xv = *(const f4*)(x     + chbase + offn); \
    NXT##_B0 = *(const f4*)(Bp + 0 * L_ + offn); \
    NXT##_B1 = *(const f4*)(Bp + 1 * L_ + offn); \
    NXT##_B2 = *(const f4*)(Bp + 2 * L_ + offn); \
    NXT##_B3 = *(const f4*)(Bp + 3 * L_ + offn); \
    NXT##_B4 = *(const f4*)(Bp + 4 * L_ + offn); \
    NXT##_B5 = *(const f4*)(Bp + 5 * L_ + offn); \
    NXT##_B6 = *(const f4*)(Bp + 6 * L_ + offn); \
    NXT##_B7 = *(const f4*)(Bp + 7 * L_ + offn); \
    /* ---- current-chunk late-use loads (L2-hot, ~1000cy of cover) ---- */ \
    f4 zv  = *(const f4*)(z + chbase + off); \
    f4 Cv0 = *(const f4*)(Cp + 0 * L_ + off); \
    f4 Cv1 = *(const f4*)(Cp + 1 * L_ + off); \
    f4 Cv2 = *(const f4*)(Cp + 2 * L_ + off); \
    f4 Cv3 = *(const f4*)(Cp + 3 * L_ + off); \
    f4 Cv4 = *(const f4*)(Cp + 4 * L_ + off); \
    f4 Cv5 = *(const f4*)(Cp + 5 * L_ + off); \
    f4 Cv6 = *(const f4*)(Cp + 6 * L_ + off); \
    f4 Cv7 = *(const f4*)(Cp + 7 * L_ + off); \
    /* ---- dt / u ---- */ \
    float dt0 = softplus_f(CUR##_dv.x + bias); \
    float dt1 = softplus_f(CUR##_dv.y + bias); \
    float dt2 = softplus_f(CUR##_dv.z + bias); \
    float dt3 = softplus_f(CUR##_dv.w + bias); \
    float u0 = dt0 * CUR##_xv.x, u1 = dt1 * CUR##_xv.y; \
    float u2 = dt2 * CUR##_xv.z, u3 = dt3 * CUR##_xv.w; \
    /* ---- per-element deltaA vectors ---- */ \
    f8 e0 = exp2v8(splat8(dt0) * A2v); \
    f8 e1 = exp2v8(splat8(dt1) * A2v); \
    f8 e2 = exp2v8(splat8(dt2) * A2v); \
    f8 e3 = exp2v8(splat8(dt3) * A2v); \
    /* ---- transpose B/C fragments to per-j state-vectors ---- */ \
    f8 tB0 = {CUR##_B0.x,CUR##_B1.x,CUR##_B2.x,CUR##_B3.x,CUR##_B4.x,CUR##_B5.x,CUR##_B6.x,CUR##_B7.x}; \
    f8 tB1 = {CUR##_B0.y,CUR##_B1.y,CUR##_B2.y,CUR##_B3.y,CUR##_B4.y,CUR##_B5.y,CUR##_B6.y,CUR##_B7.y}; \
    f8 tB2 = {CUR##_B0.z,CUR##_B1.z,CUR##_B2.z,CUR##_B3.z,CUR##_B4.z,CUR##_B5.z,CUR##_B6.z,CUR##_B7.z}; \
    f8 tB3 = {CUR##_B0.w,CUR##_B1.w,CUR##_B2.w,CUR##_B3.w,CUR##_B4.w,CUR##_B5.w,CUR##_B6.w,CUR##_B7.w}; \
    f8 SC0 = {Cv0.x,Cv1.x,Cv2.x,Cv3.x,Cv4.x,Cv5.x,Cv6.x,Cv7.x}; \
    f8 SC1 = {Cv0.y,Cv1.y,Cv2.y,Cv3.y,Cv4.y,Cv5.y,Cv6.y,Cv7.y}; \
    f8 SC2 = {Cv0.z,Cv1.z,Cv2.z,Cv3.z,Cv4.z,Cv5.z,Cv6.z,Cv7.z}; \
    f8 SC3 = {Cv0.w,Cv1.w,Cv2.w,Cv3.w,Cv4.w,Cv5.w,Cv6.w,Cv7.w}; \
    /* ---- pass 1: local scan keeping prefix products/states ---- */ \
    f8 S0v = splat8(u0) * tB0;            /* = uB0; h after elem 0 (h_in=0) */ \
    f8 F0v = e0; \
    f8 S1v = e1 * S0v + splat8(u1) * tB1;  f8 F1v = e1 * F0v; \
    f8 S2v = e2 * S1v + splat8(u2) * tB2;  f8 F2v = e2 * F1v; \
    f8 S3v = e3 * S2v + splat8(u3) * tB3;  f8 F3v = e3 * F2v; \
    /* ---- width-32 inclusive scan of (F3v,S3v) in place, all DPP/VALU ---- */ \
    SCAN_STEP_F(DPP_ROW_SHR(1)) \
    SCAN_STEP_F(DPP_ROW_SHR(2)) \
    SCAN_STEP_F(DPP_ROW_SHR(4)) \
    SCAN_STEP_F(DPP_ROW_SHR(8)) \
    SCAN_STEP_M(DPP_ROW_BCAST15, 0xA)  /* rows 1,3 only; rows 0,2 keep neutral */ \
    /* ---- fold chunk carry; h_in entering this lane's segment ---- */ \
    f8 h; f8 hincv; \
    _Pragma("unroll") \
    for (int i = 0; i < NH; ++i) { \
        hincv[i] = fmaf(carry[i], F3v[i], S3v[i]);          /* state after elem 3 */ \
        float hup = dpp0<DPP_WAVE_SHR1, 0xF>(hincv[i]);     /* lane n <- n-1 */ \
        h[i] = (s == 0) ? carry[i] : hup; \
        carry[i] = __shfl(hincv[i], 31, 32);                /* broadcast within half */ \
    } \
    /* ---- pass 2: independent per-element states; y_j = <h_j, C_j> ---- */ \
    f8 t0 = F0v * h + S0v;  float y0 = dot8(t0, SC0); \
    f8 t1 = F1v * h + S1v;  float y1 = dot8(t1, SC1); \
    f8 t2 = F2v * h + S2v;  float y2 = dot8(t2, SC2); \
    float y3 = dot8(hincv, SC3); \
    /* ---- combine the two state-halves; epilogue; half-wave store ---- */ \
    y0 += __shfl_xor(y0, 32, 64); \
    y1 += __shfl_xor(y1, 32, 64); \
    y2 += __shfl_xor(y2, 32, 64); \
    y3 += __shfl_xor(y3, 32, 64); \
    if (g == 0) { \
        float s0 = rcpf_(1.0f + exp2f_(-zv.x * LOG2E)); \
        float s1 = rcpf_(1.0f + exp2f_(-zv.y * LOG2E)); \
        float s2 = rcpf_(1.0f + exp2f_(-zv.z * LOG2E)); \
        float s3 = rcpf_(1.0f + exp2f_(-zv.w * LOG2E)); \
        f4 ov = { (y0 + CUR##_xv.x * Dd) * (zv.x * s0), \
                  (y1 + CUR##_xv.y * Dd) * (zv.y * s1), \
                  (y2 + CUR##_xv.z * Dd) * (zv.z * s2), \
                  (y3 + CUR##_xv.w * Dd) * (zv.w * s3) }; \
        *(f4*)(out + chbase + off) = ov; \
    } \
}

// Full-row-mask scan step: S-shift via bound_ctrl (single dpp-mov), P keeps
// old=1.0 (multiplicative identity).
#define SCAN_STEP_F(CTRL) \
    { \
        _Pragma("unroll") \
        for (int i = 0; i < NH; ++i) { \
            float Pp = updpp<CTRL, 0xF>(1.0f, F3v[i]); \
            float Sp = dpp0<CTRL, 0xF>(S3v[i]); \
            S3v[i] = fmaf(Sp, F3v[i], S3v[i]);   /* uses pre-update P */ \
            F3v[i] = F3v[i] * Pp; \
        } \
    }
// Masked step (bcast15): both operands need old-value semantics on the
// masked rows (0,2), which must see the neutral element.
#define SCAN_STEP_M(CTRL, RMASK) \
    { \
        _Pragma("unroll") \
        for (int i = 0; i < NH; ++i) { \
            float Pp = updpp<CTRL, RMASK>(1.0f, F3v[i]); \
            float Sp = updpp<CTRL, RMASK>(0.0f, S3v[i]); \
            S3v[i] = fmaf(Sp, F3v[i], S3v[i]); \
            F3v[i] = F3v[i] * Pp; \
        } \
    }

    for (int cc = 0; cc < NCHUNK; cc += 2) {
        BODY(cc,     P0, P1)
        BODY(cc + 1, P1, P0)
    }
}

extern "C" void kernel_launch(void* const* d_in, const int* in_sizes, int n_in,
                              void* d_out, int out_size, void* d_ws, size_t ws_size,
                              hipStream_t stream) {
    const float* x     = (const float*)d_in[0];
    const float* delta = (const float*)d_in[1];
    const float* A     = (const float*)d_in[2];
    const float* Bm    = (const float*)d_in[3];
    const float* Cm    = (const float*)d_in[4];
    const float* Dv    = (const float*)d_in[5];
    const float* z     = (const float*)d_in[6];
    const float* dbias = (const float*)d_in[7];
    float* out = (float*)d_out;

    dim3 grid(NCH);    // 3072 blocks = 1 wave = 1 channel each
    dim3 block(64);
    ssm_scan_kernel<<<grid, block, 0, stream>>>(x, delta, A, Bm, Cm, Dv, z, dbias, out);
}